// Round 7
// baseline (511.227 us; speedup 1.0000x reference)
//
#include <hip/hip_runtime.h>

#define DIM 32
#define BLOCK 256
#define RS 36     // padded LDS row stride (floats): conflict-free, float4-aligned (36 = 4*9)
#define TILES 2   // 64-row tiles per wave; block covers 4*64*TILES=512 rows; grid = 2048

// ---------------------------------------------------------------------------
// The full Gibbs sweep is affine: out = A*x + B*n + c, with
//   A = E31*...*E0,  E_i = I with row i replaced by c_i (c_ii = 0, c_ij = -P_ij/P_ii)
//   B[:,i] = s_i * (E31*...*E_{i+1}) e_i   (lower-tri incl diag, s_i = sqrt(1/P_ii))
//   c = sum_i m_i * (E31*...*E_{i+1}) e_i
// Setup computes A (col-major), B (col-major), c via 32 rank-1 updates.
// ws layout: A[1024] col-major | B[1024] col-major | c[32]  (2080 floats, 8.3 KB)
// ---------------------------------------------------------------------------
__global__ __launch_bounds__(1024) void gibbs_setup_kernel(
    const float* __restrict__ prec,
    const float* __restrict__ mu,
    float* __restrict__ ws)
{
    const int tid = threadIdx.x;
    const int k = tid >> 5;   // row of S
    const int j = tid & 31;   // col of S
    __shared__ float S[32][33];
    __shared__ float cm[32][33];
    __shared__ float coli[32];
    __shared__ float sv[32], mv[32], cacc[32];

    {
        const float pii = prec[k * DIM + k];
        cm[k][j] = (j == k) ? 0.0f : (-prec[k * DIM + j] / pii);
        S[k][j] = (j == k) ? 1.0f : 0.0f;
        if (j == 0) {
            sv[k] = sqrtf(1.0f / pii);
            mv[k] = mu[k];
            cacc[k] = 0.0f;
        }
    }
    __syncthreads();

    for (int i = 31; i >= 0; --i) {
        // At loop entry S == S_i = E31*...*E_{i+1}. Record B col i, c contribution.
        if (j == 0) {
            const float ski = S[k][i];
            coli[k] = ski;                         // stash old col i for the rank-1 update
            ws[1024 + i * 32 + k] = sv[i] * ski;   // B col-major
            cacc[k] += mv[i] * ski;
        }
        __syncthreads();
        // S <- S * E_i :  S[k][j] += S[k][i]_old * (c_ij - delta_ij)
        S[k][j] += coli[k] * (cm[i][j] - ((j == i) ? 1.0f : 0.0f));
        __syncthreads();   // update(iter i) complete before record(iter i-1)
    }
    ws[j * 32 + k] = S[k][j];                      // A col-major
    if (j == 0) ws[2048 + k] = cacc[k];
}

// ---------------------------------------------------------------------------
// Sweep: 1 row/lane, per-wave padded LDS chunk (no cross-wave sharing -> no
// barriers; DS ops are in-order within a wave). One 8xfloat4 register array
// time-shares three roles so only 32 prefetch VGPRs are ever live:
//   write vx(t)->LDS | load vn(t) | pass1 A*x | write vn->LDS | load vx(t+1)
//   | pass2 B*n | store out(t)
// Loads are always in flight under 1500-3100 cycles of independent FMAs.
// ---------------------------------------------------------------------------
__global__ __launch_bounds__(BLOCK, 4) void gibbs_sweep_kernel(
    const float* __restrict__ x,
    const float* __restrict__ noise,
    const float* __restrict__ ws,
    float* __restrict__ out)
{
    __shared__ float lds[4][64 * RS];   // 4 waves * 9216 B = 36 KB/block

    const float* __restrict__ Acm = ws;          // Acm[j*32+k] = A[k][j]
    const float* __restrict__ Bcm = ws + 1024;   // Bcm[j*32+k] = B[k][j], lower-tri
    const float* __restrict__ cv  = ws + 2048;

    const int wid  = threadIdx.x >> 6;
    const int lane = threadIdx.x & 63;
    const long w = (long)blockIdx.x * 4 + wid;   // global wave id

    const float4* __restrict__ xg = (const float4*)x;
    const float4* __restrict__ ng = (const float4*)noise;
    float4* __restrict__ og = (float4*)out;

    float* L = lds[wid];

    // Prologue: tile 0 x loads (coalesced: lane l -> float4 k*64+l, 1 KB/instr).
    float4 v[8];
    {
        const long b0 = w * (long)TILES * 512;   // 512 float4 per 64x32 tile
#pragma unroll
        for (int k = 0; k < 8; ++k) v[k] = xg[b0 + k * 64 + lane];
    }

#pragma unroll
    for (int t = 0; t < TILES; ++t) {
        const long bcur = (w * TILES + t) * 512L;
        const bool more = (t + 1 < TILES);

        // ---- vx(t): regs -> padded LDS (chunk f -> row f>>3, quad f&7) ----
#pragma unroll
        for (int k = 0; k < 8; ++k) {
            const int f = k * 64 + lane;
            *(float4*)(L + (f >> 3) * RS + (f & 7) * 4) = v[k];
        }
        // regs free -> issue vn(t) loads now; latency hides under pass 1.
#pragma unroll
        for (int k = 0; k < 8; ++k) v[k] = ng[bcur + k * 64 + lane];
        __builtin_amdgcn_sched_barrier(0);   // keep these loads issued up here

        float acc[DIM];
#pragma unroll
        for (int k = 0; k < DIM; ++k) acc[k] = cv[k];

        // ---- pass 1: acc += A * x_row (A cols wave-uniform -> scalar loads) ----
#pragma unroll
        for (int c = 0; c < 8; ++c) {
            const float4 q = *(const float4*)(L + lane * RS + c * 4);
            const float qs[4] = {q.x, q.y, q.z, q.w};
#pragma unroll
            for (int tt = 0; tt < 4; ++tt) {
                const int j = c * 4 + tt;
                const float* __restrict__ aj = Acm + j * 32;
#pragma unroll
                for (int k = 0; k < 32; ++k) acc[k] = fmaf(qs[tt], aj[k], acc[k]);
            }
        }

        // ---- vn(t): regs -> LDS (DS in-order: writes queue after pass-1 reads) ----
#pragma unroll
        for (int k = 0; k < 8; ++k) {
            const int f = k * 64 + lane;
            *(float4*)(L + (f >> 3) * RS + (f & 7) * 4) = v[k];
        }
        // regs free -> issue vx(t+1) loads; latency hides under pass 2.
        if (more) {
            const long bnext = bcur + 512;
#pragma unroll
            for (int k = 0; k < 8; ++k) v[k] = xg[bnext + k * 64 + lane];
            __builtin_amdgcn_sched_barrier(0);
        }

        // ---- pass 2: acc += B * n_row (B lower-tri: k >= j) ----
#pragma unroll
        for (int c = 0; c < 8; ++c) {
            const float4 q = *(const float4*)(L + lane * RS + c * 4);
            const float qs[4] = {q.x, q.y, q.z, q.w};
#pragma unroll
            for (int tt = 0; tt < 4; ++tt) {
                const int j = c * 4 + tt;
                const float* __restrict__ bj = Bcm + j * 32;
#pragma unroll
                for (int k = j; k < 32; ++k) acc[k] = fmaf(qs[tt], bj[k], acc[k]);
            }
        }

        // ---- stores: direct strided from registers (R0-verified clean traffic) ----
        const long rb = ((w * TILES + t) * 64 + lane) * 8;
#pragma unroll
        for (int kk = 0; kk < 8; ++kk)
            og[rb + kk] = make_float4(acc[kk * 4], acc[kk * 4 + 1],
                                      acc[kk * 4 + 2], acc[kk * 4 + 3]);
    }
}

extern "C" void kernel_launch(void* const* d_in, const int* in_sizes, int n_in,
                              void* d_out, int out_size, void* d_ws, size_t ws_size,
                              hipStream_t stream) {
    const float* x     = (const float*)d_in[0];  // (B, 32)
    const float* noise = (const float*)d_in[1];  // (B, 32)
    const float* prec  = (const float*)d_in[2];  // (32, 32)
    const float* mu    = (const float*)d_in[3];  // (32,)
    float* out = (float*)d_out;
    float* ws  = (float*)d_ws;                   // needs 2080 floats (8.3 KB)

    const int B = in_sizes[0] / DIM;             // 1048576
    const int grid = B / (BLOCK * TILES);        // 2048 blocks

    gibbs_setup_kernel<<<1, 1024, 0, stream>>>(prec, mu, ws);
    gibbs_sweep_kernel<<<grid, BLOCK, 0, stream>>>(x, noise, ws, out);
}

// Round 8
// 335.108 us; speedup vs baseline: 1.5256x; 1.5256x over previous
//
#include <hip/hip_runtime.h>

#define DIM 32
#define BLOCK 256
#define RS 36     // padded LDS row stride (floats): R1-proven conflict-free patterns

// ---------------------------------------------------------------------------
// The full Gibbs sweep is affine: out = A*x + B*n + c, with
//   A = E31*...*E0,  E_i = I with row i replaced by c_i (c_ii = 0, c_ij = -P_ij/P_ii)
//   B[:,i] = s_i * (E31*...*E_{i+1}) e_i   (lower-tri incl diag, s_i = sqrt(1/P_ii))
//   c = sum_i m_i * (E31*...*E_{i+1}) e_i
// ws layout: A[1024] col-major | B[1024] col-major | c[32]  (2080 floats)
// Verified correct in round 7 (passed, absmax = baseline).
// ---------------------------------------------------------------------------
__global__ __launch_bounds__(1024) void gibbs_setup_kernel(
    const float* __restrict__ prec,
    const float* __restrict__ mu,
    float* __restrict__ ws)
{
    const int tid = threadIdx.x;
    const int k = tid >> 5;   // row of S
    const int j = tid & 31;   // col of S
    __shared__ float S[32][33];
    __shared__ float cm[32][33];
    __shared__ float coli[32];
    __shared__ float sv[32], mv[32], cacc[32];

    {
        const float pii = prec[k * DIM + k];
        cm[k][j] = (j == k) ? 0.0f : (-prec[k * DIM + j] / pii);
        S[k][j] = (j == k) ? 1.0f : 0.0f;
        if (j == 0) {
            sv[k] = sqrtf(1.0f / pii);
            mv[k] = mu[k];
            cacc[k] = 0.0f;
        }
    }
    __syncthreads();

    for (int i = 31; i >= 0; --i) {
        if (j == 0) {
            const float ski = S[k][i];
            coli[k] = ski;                         // stash old col i
            ws[1024 + i * 32 + k] = sv[i] * ski;   // B col-major
            cacc[k] += mv[i] * ski;
        }
        __syncthreads();
        S[k][j] += coli[k] * (cm[i][j] - ((j == i) ? 1.0f : 0.0f));
        __syncthreads();
    }
    ws[j * 32 + k] = S[k][j];                      // A col-major
    if (j == 0) ws[2048 + k] = cacc[k];
}

// ---------------------------------------------------------------------------
// Sweep: 1 row/lane. Phases keep peak live regs < 64 BY CONSTRUCTION
// (R4/R7 lesson: acc[32] + 32 prefetch regs live together => scratch spill):
//   [x: 8 coalesced loads -> regs -> padded LDS]   (v[8] dies before acc born)
//   [acc = c]
//   [jobs 0..7:  dense A cols, x quad j from LDS; nq pipe starts at job 6]
//   [jobs 8..15: lower-tri B cols, n quad m from depth-3 strided reg pipe]
//   [out: acc -> LDS -> coalesced stores]
// Per-wave LDS chunk, no cross-wave sharing -> no barriers (DS in-order).
// ---------------------------------------------------------------------------
__global__ __launch_bounds__(BLOCK, 4) void gibbs_sweep_kernel(
    const float* __restrict__ x,
    const float* __restrict__ noise,
    const float* __restrict__ ws,
    float* __restrict__ out)
{
    __shared__ float lds[4][64 * RS];   // 4 waves * 9216 B = 36 KB/block

    const float* __restrict__ Acm = ws;          // Acm[j*32+k] = A[k][j]
    const float* __restrict__ Bcm = ws + 1024;   // Bcm[j*32+k] = B[k][j], lower-tri
    const float* __restrict__ cv  = ws + 2048;

    const int wid  = threadIdx.x >> 6;
    const int lane = threadIdx.x & 63;
    const long w = (long)blockIdx.x * 4 + wid;   // global wave id
    const long rowbase = w * 64;                 // wave's first row

    const float4* __restrict__ xw = (const float4*)(x + rowbase * DIM);          // wave span
    const float4* __restrict__ nr = (const float4*)(noise + (rowbase + lane) * DIM); // lane's row
    float4* __restrict__ ow = (float4*)(out + rowbase * DIM);

    float* L = lds[wid];

    // ---- stage x: coalesced (lane l -> float4 k*64+l, 1 KB/instr) -> LDS ----
    {
        float4 v[8];
#pragma unroll
        for (int k = 0; k < 8; ++k) v[k] = xw[k * 64 + lane];
#pragma unroll
        for (int k = 0; k < 8; ++k) {
            const int f = k * 64 + lane;
            *(float4*)(L + (f >> 3) * RS + (f & 7) * 4) = v[k];
        }
    }   // v dead here: staging-phase peak ~44 VGPRs, acc not yet live

    float acc[DIM];
#pragma unroll
    for (int k = 0; k < DIM; ++k) acc[k] = cv[k];

    float4 nq[3];   // depth-3 rotating strided-n pipe (all indices compile-time)

    // ---- jobs 0..7: acc += A[:,4j..4j+3] * x-quad-j (from LDS) ----
#pragma unroll
    for (int j = 0; j < 8; ++j) {
        if (j >= 6) nq[(j - 6) % 3] = nr[j - 6];   // nq0 @job6, nq1 @job7
        const float4 q = *(const float4*)(L + lane * RS + j * 4);
        const float qs[4] = {q.x, q.y, q.z, q.w};
#pragma unroll
        for (int tt = 0; tt < 4; ++tt) {
            const float* __restrict__ aj = Acm + (j * 4 + tt) * 32;
#pragma unroll
            for (int k = 0; k < 32; ++k) acc[k] = fmaf(qs[tt], aj[k], acc[k]);
        }
        __builtin_amdgcn_sched_barrier(0);   // bound load motion both directions
    }

    // ---- jobs 8..15: acc += B[:,4m..4m+3] * n-quad-m (lower-tri: k >= col) ----
#pragma unroll
    for (int m = 0; m < 8; ++m) {
        if (m + 2 < 8) nq[(m + 2) % 3] = nr[m + 2];   // stay 2 jobs ahead
        const float4 q = nq[m % 3];
        const float qs[4] = {q.x, q.y, q.z, q.w};
#pragma unroll
        for (int tt = 0; tt < 4; ++tt) {
            const int col = m * 4 + tt;
            const float* __restrict__ bj = Bcm + col * 32;
#pragma unroll
            for (int k = col; k < 32; ++k) acc[k] = fmaf(qs[tt], bj[k], acc[k]);
        }
        __builtin_amdgcn_sched_barrier(0);
    }

    // ---- out: acc -> padded LDS -> coalesced stores (R1-proven exact traffic) ----
#pragma unroll
    for (int c = 0; c < 8; ++c)
        *(float4*)(L + lane * RS + c * 4) =
            make_float4(acc[c * 4], acc[c * 4 + 1], acc[c * 4 + 2], acc[c * 4 + 3]);
#pragma unroll
    for (int k = 0; k < 8; ++k) {
        const int f = k * 64 + lane;
        ow[k * 64 + lane] = *(const float4*)(L + (f >> 3) * RS + (f & 7) * 4);
    }
}

extern "C" void kernel_launch(void* const* d_in, const int* in_sizes, int n_in,
                              void* d_out, int out_size, void* d_ws, size_t ws_size,
                              hipStream_t stream) {
    const float* x     = (const float*)d_in[0];  // (B, 32)
    const float* noise = (const float*)d_in[1];  // (B, 32)
    const float* prec  = (const float*)d_in[2];  // (32, 32)
    const float* mu    = (const float*)d_in[3];  // (32,)
    float* out = (float*)d_out;
    float* ws  = (float*)d_ws;                   // needs 2080 floats (8.3 KB)

    const int B = in_sizes[0] / DIM;             // 1048576
    const int grid = B / BLOCK;                  // 4096 blocks

    gibbs_setup_kernel<<<1, 1024, 0, stream>>>(prec, mu, ws);
    gibbs_sweep_kernel<<<grid, BLOCK, 0, stream>>>(x, noise, ws, out);
}